// Round 5
// baseline (376.661 us; speedup 1.0000x reference)
//
#include <hip/hip_runtime.h>
#include <math.h>

// Problem constants (B,C,L,K) = (32, 64, 4096, 512)
#define B_DIM 32
#define C_DIM 64
#define L_DIM 4096
#define K_CB  512
#define N_ROWS (B_DIM * L_DIM)            // 131072
#define Q_ELEMS (B_DIM * C_DIM * L_DIM)   // 8388608

// Output layout (float32, concatenated in return order):
// loss(1), quantized_st(B,C,L), perplexity(1), embed(K,C), indices(B,L), encodings(N,K)
#define OFF_LOSS  0
#define OFF_Q     1
#define OFF_PERP  (1 + Q_ELEMS)
#define OFF_EMBED (OFF_PERP + 1)
#define OFF_IDX   (OFF_EMBED + K_CB * C_DIM)
#define OFF_ENC   (OFF_IDX + N_ROWS)

#define RPB 128   // rows per block == threads per block (one row per thread)

using f2 = __attribute__((ext_vector_type(2))) float;

// ws layout: [0:8) double loss; [16:16+2048) int hist[512]; [4096:+2048) float esq[512]

__global__ void vq_init(const float* __restrict__ embed,
                        double* __restrict__ loss_ws,
                        int* __restrict__ hist,
                        float* __restrict__ esq,
                        float* __restrict__ out_embed) {
  const int t = threadIdx.x;  // 512 threads, 1 block
  if (t == 0) *loss_ws = 0.0;
  hist[t] = 0;
  const float* row = embed + (size_t)t * C_DIM;
  float s = 0.f;
#pragma unroll
  for (int c = 0; c < C_DIM; ++c) s = fmaf(row[c], row[c], s);
  esq[t] = s;
#pragma unroll
  for (int i = 0; i < K_CB * C_DIM / 512; ++i)
    out_embed[i * 512 + t] = embed[i * 512 + t];
}

// ---------------------------------------------------------------------------
// Fused VQ, one row per thread. GEMM phase: x in 64 registers (static idx),
// e via wave-uniform scalar loads (SMEM pipe) -> no LDS, no barriers, no
// cross-lane reduce in the hot loop. Epilogue: cooperative quant + one-hot.
// ---------------------------------------------------------------------------
__global__ __launch_bounds__(128) void vq_fused(
    const float* __restrict__ in, const float* __restrict__ embed,
    const float* __restrict__ esq_g, int* __restrict__ hist,
    double* __restrict__ loss_ws, float* __restrict__ out) {
  __shared__ float  eSel[64 * C_DIM];  // 16 KB, selected codewords (2 passes)
  __shared__ int    idx_s[RPB];
  __shared__ double red[RPB];

  const int tid = threadIdx.x;
  const int blk = blockIdx.x;            // 1024 blocks
  const int b   = blk >> 5;              // 32 blocks per batch element
  const int l0  = (blk & 31) * RPB;
  const int l   = l0 + tid;              // this thread's row (lane-consecutive)

  // --- load x row into registers (coalesced 512B per wave-instr) ---
  const float* xp = in + (size_t)b * (C_DIM * L_DIM) + l;
  float x[C_DIM];
#pragma unroll
  for (int c = 0; c < C_DIM; ++c) x[c] = xp[(size_t)c * L_DIM];

  // flat_sq: sequential fmaf chain ascending c (bit-matches prior rounds)
  float fs = 0.f;
#pragma unroll
  for (int c = 0; c < C_DIM; ++c) fs = fmaf(x[c], x[c], fs);

  // --- argmin over 512 codewords, 4 at a time; e loads are wave-uniform ---
  float rmin = 3.402823466e38f;
  int   ridx = 0;
  for (int g = 0; g < K_CB / 4; ++g) {   // 128 groups
    const float* e0 = embed + (size_t)g * 4 * C_DIM;   // uniform -> s_load
    float a0 = 0.f, a1 = 0.f, a2 = 0.f, a3 = 0.f;
#pragma unroll
    for (int c = 0; c < C_DIM; ++c) {
      const float xv = x[c];
      a0 = fmaf(xv, e0[c], a0);
      a1 = fmaf(xv, e0[C_DIM + c], a1);
      a2 = fmaf(xv, e0[2 * C_DIM + c], a2);
      a3 = fmaf(xv, e0[3 * C_DIM + c], a3);
    }
    const int k0 = g * 4;
    // d = (fs + esq) - 2*dot, single rounding via fma (same as prior rounds);
    // strict <, ascending k: first-minimum semantics preserved.
    const float d0 = fmaf(-2.0f, a0, fs + esq_g[k0 + 0]);
    if (d0 < rmin) { rmin = d0; ridx = k0 + 0; }
    const float d1 = fmaf(-2.0f, a1, fs + esq_g[k0 + 1]);
    if (d1 < rmin) { rmin = d1; ridx = k0 + 1; }
    const float d2 = fmaf(-2.0f, a2, fs + esq_g[k0 + 2]);
    if (d2 < rmin) { rmin = d2; ridx = k0 + 2; }
    const float d3 = fmaf(-2.0f, a3, fs + esq_g[k0 + 3]);
    if (d3 < rmin) { rmin = d3; ridx = k0 + 3; }
  }

  // --- indices + histogram ---
  out[OFF_IDX + blk * RPB + tid] = (float)ridx;
  atomicAdd(&hist[ridx], 1);
  idx_s[tid] = ridx;

  // --- quantized_st + loss, 2 passes of 64 rows through eSel ---
  double ls = 0.0;
  {
    float* qbase = out + OFF_Q + (size_t)b * (C_DIM * L_DIM) + l0;
    const int cc = tid & 63;
    const int w  = tid >> 6;  // wave id 0..1
#pragma unroll
    for (int pass = 0; pass < 2; ++pass) {
      const int r0 = pass * 64;
      __syncthreads();  // idx_s ready (pass 0) / previous eSel readers done
      // stage selected codewords, swizzled: eSel[r][c ^ (r&31)], coalesced reads
#pragma unroll 4
      for (int it = 0; it < 32; ++it) {
        const int r = it * 2 + w;
        const int k = idx_s[r0 + r];
        eSel[r * C_DIM + (cc ^ (r & 31))] = embed[(size_t)k * C_DIM + cc];
      }
      __syncthreads();
      // 64 rows x 64 c = 4096 elems, 32 iters of 128 threads
#pragma unroll 4
      for (int it = 0; it < 32; ++it) {
        const int f = it * 128 + tid;
        const int c = f >> 6;        // wave-uniform
        const int r = f & 63;        // lane-consecutive -> coalesced
        const float xx = in[(size_t)b * (C_DIM * L_DIM) + (size_t)c * L_DIM + l0 + r0 + r];
        const float q  = eSel[r * C_DIM + (c ^ (r & 31))];  // 2-way bank (free)
        const float d  = q - xx;
        __builtin_nontemporal_store(xx + d, qbase + (size_t)c * L_DIM + r0 + r);
        ls += (double)(d * d);
      }
    }
  }

  // --- one-hot encodings: one row per iteration (idx broadcast), f2 stores ---
  {
    f2* enc = (f2*)(out + OFF_ENC) + (size_t)blk * RPB * (K_CB / 2);
#pragma unroll 4
    for (int it = 0; it < RPB; ++it) {
      const int k = idx_s[it];
      {
        const int j2 = tid << 1;
        f2 v;
        v.x = (j2 == k)     ? 1.0f : 0.0f;
        v.y = (j2 + 1 == k) ? 1.0f : 0.0f;
        __builtin_nontemporal_store(v, enc + it * 256 + tid);
      }
      {
        const int j2 = (tid + 128) << 1;
        f2 v;
        v.x = (j2 == k)     ? 1.0f : 0.0f;
        v.y = (j2 + 1 == k) ? 1.0f : 0.0f;
        __builtin_nontemporal_store(v, enc + it * 256 + 128 + tid);
      }
    }
  }

  // --- loss block-reduce (double) ---
  red[tid] = ls;
  __syncthreads();
  for (int s = 64; s; s >>= 1) {
    if (tid < s) red[tid] += red[tid + s];
    __syncthreads();
  }
  if (tid == 0) atomicAdd(loss_ws, red[0]);
}

__global__ void vq_final(const int* __restrict__ hist, const double* __restrict__ loss_ws,
                         float* __restrict__ out) {
  __shared__ float red[512];
  const int t = threadIdx.x;
  const float p = (float)hist[t] * (1.0f / (float)N_ROWS);
  red[t] = p * logf(p + 1e-10f);
  __syncthreads();
  for (int s = 256; s; s >>= 1) {
    if (t < s) red[t] += red[t + s];
    __syncthreads();
  }
  if (t == 0) {
    out[OFF_PERP] = expf(-red[0]);
    const float m = (float)(*loss_ws / (double)Q_ELEMS);
    out[OFF_LOSS] = m + 0.25f * m;
  }
}

extern "C" void kernel_launch(void* const* d_in, const int* in_sizes, int n_in,
                              void* d_out, int out_size, void* d_ws, size_t ws_size,
                              hipStream_t stream) {
  (void)in_sizes; (void)n_in; (void)out_size; (void)ws_size;
  const float* in    = (const float*)d_in[0];
  const float* embed = (const float*)d_in[1];
  float* out = (float*)d_out;

  double* loss_ws = (double*)d_ws;
  int*    hist    = (int*)((char*)d_ws + 16);
  float*  esq     = (float*)((char*)d_ws + 4096);

  vq_init<<<1, 512, 0, stream>>>(embed, loss_ws, hist, esq, out + OFF_EMBED);
  vq_fused<<<N_ROWS / RPB, RPB, 0, stream>>>(in, embed, esq, hist, loss_ws, out);
  vq_final<<<1, 512, 0, stream>>>(hist, loss_ws, out);
}

// Round 6
// 209.104 us; speedup vs baseline: 1.8013x; 1.8013x over previous
//
#include <hip/hip_runtime.h>
#include <math.h>

// Problem constants (B,C,L,K) = (32, 64, 4096, 512)
#define B_DIM 32
#define C_DIM 64
#define L_DIM 4096
#define K_CB  512
#define N_ROWS (B_DIM * L_DIM)            // 131072
#define Q_ELEMS (B_DIM * C_DIM * L_DIM)   // 8388608

// Output layout (float32, concatenated in return order):
// loss(1), quantized_st(B,C,L), perplexity(1), embed(K,C), indices(B,L), encodings(N,K)
#define OFF_LOSS  0
#define OFF_Q     1
#define OFF_PERP  (1 + Q_ELEMS)
#define OFF_EMBED (OFF_PERP + 1)
#define OFF_IDX   (OFF_EMBED + K_CB * C_DIM)
#define OFF_ENC   (OFF_IDX + N_ROWS)

#define TPB     128   // threads per block (2 waves)
#define RPB     256   // rows per block (2 per thread)
#define KCHUNK  128   // codewords per LDS chunk (4 chunks)

using f4 = __attribute__((ext_vector_type(4))) float;
using f2 = __attribute__((ext_vector_type(2))) float;

// ws layout: [0:8) double loss; [16:16+2048) int hist[512]; [4096:+2048) float esq[512]

__global__ void vq_init(const float* __restrict__ embed,
                        double* __restrict__ loss_ws,
                        int* __restrict__ hist,
                        float* __restrict__ esq,
                        float* __restrict__ out_embed) {
  const int t = threadIdx.x;  // 512 threads, 1 block
  if (t == 0) *loss_ws = 0.0;
  hist[t] = 0;
  const float* row = embed + (size_t)t * C_DIM;
  float s = 0.f;
#pragma unroll
  for (int c = 0; c < C_DIM; ++c) s = fmaf(row[c], row[c], s);
  esq[t] = s;
#pragma unroll
  for (int i = 0; i < K_CB * C_DIM / 512; ++i)
    out_embed[i * 512 + t] = embed[i * 512 + t];
}

// ---------------------------------------------------------------------------
// Fused VQ. Each thread owns 2 rows; x lives in registers (64 x f2).
// e chunks staged in LDS, read with WAVE-UNIFORM addresses (broadcast, no
// bank traffic) -> GEMM is pure-VALU bound. enc zero-fill is interleaved
// into the GEMM so its 256 MB of HBM writes overlap compute; the single
// 1.0f per row is written after vmcnt(0)+barrier ordering.
// ---------------------------------------------------------------------------
__global__ __launch_bounds__(TPB) void vq_fused(
    const float* __restrict__ in, const float* __restrict__ embed,
    const float* __restrict__ esq_g, int* __restrict__ hist,
    double* __restrict__ loss_ws, float* __restrict__ out) {
  __shared__ float  eT[KCHUNK * C_DIM];  // 32 KB, linear [k][c]
  __shared__ float  esq_s[KCHUNK];
  __shared__ double red[TPB];

  const int tid = threadIdx.x;
  const int blk = blockIdx.x;            // 512 blocks
  const int b   = blk >> 4;              // 16 blocks per batch element
  const int l0  = (blk & 15) * RPB;
  const int l   = l0 + 2 * tid;          // rows l, l+1 owned by this thread

  // --- load 2 x-rows into registers (f2, coalesced 8B/lane) ---
  const float* xp = in + (size_t)b * (C_DIM * L_DIM) + l;
  f2 x[C_DIM];
#pragma unroll
  for (int c = 0; c < C_DIM; ++c) x[c] = *(const f2*)(xp + (size_t)c * L_DIM);

  // flat_sq: sequential fmaf chain ascending c (bit-matches prior rounds)
  float fs0 = 0.f, fs1 = 0.f;
#pragma unroll
  for (int c = 0; c < C_DIM; ++c) {
    fs0 = fmaf(x[c].x, x[c].x, fs0);
    fs1 = fmaf(x[c].y, x[c].y, fs1);
  }

  f2* encz = (f2*)(out + OFF_ENC) + (size_t)blk * RPB * (K_CB / 2);
  f2 zz; zz.x = 0.f; zz.y = 0.f;

  float rmin0 = 3.402823466e38f, rmin1 = 3.402823466e38f;
  int   ridx0 = 0, ridx1 = 0;

  for (int kc = 0; kc < K_CB / KCHUNK; ++kc) {
    const int k0 = kc * KCHUNK;
    __syncthreads();  // previous chunk's readers done
    // Stage e chunk linear (coalesced f4): 8192 floats = 16 x 128thr x f4
#pragma unroll
    for (int i = 0; i < 16; ++i) {
      const int o = i * 512 + tid * 4;
      *(f4*)&eT[o] = *(const f4*)(embed + (size_t)k0 * C_DIM + o);
    }
    esq_s[tid] = esq_g[k0 + tid];
    __syncthreads();

    for (int kk = 0; kk < KCHUNK; kk += 8) {   // 16 groups of 8 codewords
      float a0[8], a1[8];
#pragma unroll
      for (int j = 0; j < 8; ++j) { a0[j] = 0.f; a1[j] = 0.f; }
#pragma unroll
      for (int cq = 0; cq < 16; ++cq) {        // c in quads, ascending
        f4 ev[8];
#pragma unroll
        for (int j = 0; j < 8; ++j)
          ev[j] = *(const f4*)&eT[(kk + j) * C_DIM + cq * 4];  // uniform -> broadcast
#pragma unroll
        for (int q = 0; q < 4; ++q) {
          const f2 xv = x[cq * 4 + q];
#pragma unroll
          for (int j = 0; j < 8; ++j) {
            a0[j] = fmaf(xv.x, ev[j][q], a0[j]);
            a1[j] = fmaf(xv.y, ev[j][q], a1[j]);
          }
        }
      }
      // enc zero-fill slice: 8 f2 nt-stores, overlaps HBM under compute
      {
        const int g = (k0 + kk) >> 3;  // 0..63
#pragma unroll
        for (int s = 0; s < 8; ++s)
          __builtin_nontemporal_store(zz, encz + (size_t)(g * 8 + s) * TPB + tid);
      }
      // min-update, ascending k, strict < : first-minimum semantics
#pragma unroll
      for (int j = 0; j < 8; ++j) {
        const int k = k0 + kk + j;
        const float es = esq_s[kk + j];
        const float d0 = fmaf(-2.0f, a0[j], fs0 + es);
        if (d0 < rmin0) { rmin0 = d0; ridx0 = k; }
        const float d1 = fmaf(-2.0f, a1[j], fs1 + es);
        if (d1 < rmin1) { rmin1 = d1; ridx1 = k; }
      }
    }
  }

  // --- indices (f2 pair store) + histogram ---
  {
    f2 iv; iv.x = (float)ridx0; iv.y = (float)ridx1;
    *(f2*)&out[OFF_IDX + blk * RPB + 2 * tid] = iv;
    atomicAdd(&hist[ridx0], 1);
    atomicAdd(&hist[ridx1], 1);
  }

  // --- enc "1" writes: ordered after all zero-fill stores of this block ---
  asm volatile("s_waitcnt vmcnt(0)" ::: "memory");
  __syncthreads();
  {
    float* encb = out + OFF_ENC + (size_t)blk * RPB * K_CB;
    encb[(size_t)(2 * tid) * K_CB + ridx0]     = 1.0f;  // regular (late-writer) stores
    encb[(size_t)(2 * tid + 1) * K_CB + ridx1] = 1.0f;
  }

  // --- quantized_st + loss from registers; e rows gathered (L2-resident) ---
  double ls = 0.0;
  {
    float* qbase = out + OFF_Q + (size_t)b * (C_DIM * L_DIM) + l;
    const float* e0 = embed + (size_t)ridx0 * C_DIM;
    const float* e1 = embed + (size_t)ridx1 * C_DIM;
#pragma unroll
    for (int c = 0; c < C_DIM; ++c) {
      const float q0 = e0[c], q1 = e1[c];
      const float d0 = q0 - x[c].x;
      const float d1 = q1 - x[c].y;
      // OFF_Q is odd -> 4B alignment only: two scalar nt-stores (stride-2,
      // merged to full sectors in L2 before HBM)
      __builtin_nontemporal_store(x[c].x + d0, qbase + (size_t)c * L_DIM);
      __builtin_nontemporal_store(x[c].y + d1, qbase + (size_t)c * L_DIM + 1);
      ls += (double)(d0 * d0);
      ls += (double)(d1 * d1);
    }
  }

  // --- loss block-reduce (double) ---
  red[tid] = ls;
  __syncthreads();
  for (int s = 64; s; s >>= 1) {
    if (tid < s) red[tid] += red[tid + s];
    __syncthreads();
  }
  if (tid == 0) atomicAdd(loss_ws, red[0]);
}

__global__ void vq_final(const int* __restrict__ hist, const double* __restrict__ loss_ws,
                         float* __restrict__ out) {
  __shared__ float red[512];
  const int t = threadIdx.x;
  const float p = (float)hist[t] * (1.0f / (float)N_ROWS);
  red[t] = p * logf(p + 1e-10f);
  __syncthreads();
  for (int s = 256; s; s >>= 1) {
    if (t < s) red[t] += red[t + s];
    __syncthreads();
  }
  if (t == 0) {
    out[OFF_PERP] = expf(-red[0]);
    const float m = (float)(*loss_ws / (double)Q_ELEMS);
    out[OFF_LOSS] = m + 0.25f * m;
  }
}

extern "C" void kernel_launch(void* const* d_in, const int* in_sizes, int n_in,
                              void* d_out, int out_size, void* d_ws, size_t ws_size,
                              hipStream_t stream) {
  (void)in_sizes; (void)n_in; (void)out_size; (void)ws_size;
  const float* in    = (const float*)d_in[0];
  const float* embed = (const float*)d_in[1];
  float* out = (float*)d_out;

  double* loss_ws = (double*)d_ws;
  int*    hist    = (int*)((char*)d_ws + 16);
  float*  esq     = (float*)((char*)d_ws + 4096);

  vq_init<<<1, 512, 0, stream>>>(embed, loss_ws, hist, esq, out + OFF_EMBED);
  vq_fused<<<N_ROWS / RPB, TPB, 0, stream>>>(in, embed, esq, hist, loss_ws, out);
  vq_final<<<1, 512, 0, stream>>>(hist, loss_ws, out);
}